// Round 6
// baseline (351.972 us; speedup 1.0000x reference)
//
#include <hip/hip_runtime.h>
#include <hip/hip_fp16.h>

#define B_ 4
#define S_ 2048
#define H_ 1024
#define M_ (B_ * S_)  // 8192 flattened rows of x / q / k / v

typedef _Float16 f16;
typedef _Float16 f16x8 __attribute__((ext_vector_type(8)));
typedef _Float16 f16x4 __attribute__((ext_vector_type(4)));
typedef float f32x4 __attribute__((ext_vector_type(4)));
typedef float f32x16 __attribute__((ext_vector_type(16)));

typedef __attribute__((address_space(3))) unsigned int* lds_u32p;
typedef const __attribute__((address_space(1))) unsigned int* gbl_u32p;

// async global->LDS, 16B per lane; LDS dest is wave-uniform base + lane*16
__device__ __forceinline__ void stage16(const f16* g, f16* l) {
  __builtin_amdgcn_global_load_lds((gbl_u32p)g, (lds_u32p)l, 16, 0, 0);
}

// ---------------------------------------------------------------------------
// One launch: x (8192 blocks) then Wq/Wk/Wv (1024 blocks each) -> fp16 RNE.
__global__ __launch_bounds__(256) void downconvert_all(
    const float* __restrict__ x, const float* __restrict__ W0,
    const float* __restrict__ W1, const float* __restrict__ W2,
    f16* __restrict__ xh, f16* __restrict__ Wh) {
  const int b = blockIdx.x;
  const float* src;
  f16* dst;
  long i;
  if (b < M_ * H_ / 1024) {  // 8192 x-blocks
    src = x; dst = xh;
    i = (long)b * 256 + threadIdx.x;
  } else {
    const int wb = b - M_ * H_ / 1024;
    const int sel = wb >> 10;               // 1024 blocks per W
    src = sel == 0 ? W0 : (sel == 1 ? W1 : W2);
    dst = Wh + (long)sel * H_ * H_;
    i = (long)(wb & 1023) * 256 + threadIdx.x;
  }
  f32x4 v = ((const f32x4*)src)[i];
  f16x4 h;
#pragma unroll
  for (int c = 0; c < 4; c++) h[c] = (f16)v[c];
  ((f16x4*)dst)[i] = h;
}

// ---------------------------------------------------------------------------
// K-chunk-major LDS tile for a 128-row x BK=64 block:
//   16B chunk L = kchunk*128 + row   (kchunk 0..7 over 64 halfs, row 0..127)
// Staging identity: thread t, call c  ->  global [t&127][kchunk=c*2+(t>>7)],
// LDS chunk c*256+t.  Fragment reads are lane-contiguous 512B per half-wave
// (canonical conflict-free b128); global side still covers each 128B
// row-segment exactly once per iter.
__device__ __forceinline__ void stage_kmajor(const f16* base, long ld, int k0,
                                             int t, f16* lds) {
  const int row = t & 127;
  const int kc0 = t >> 7;  // 0 or 1
#pragma unroll
  for (int c = 0; c < 4; c++)
    stage16(base + (long)row * ld + k0 + (c * 2 + kc0) * 8,
            lds + (c * 256 + t) * 8);
}

// ---------------------------------------------------------------------------
// Fused QKV projection, 32x32x16 MFMA, K-major LDS.
// qkv[sel][m][n] = fp16round( x[m][:] . W_sel[n][:] + b_sel[n] ); pure fp16.
// NT GEMM, 128x128 tile, BK=64. Per wave: 64x64 = 2x2 of 32x32.
// Fragments: A[m=lane&31][k=(lane>>5)*8+j]; C/D col=lane&31,
// row=(reg&3)+8*(reg>>2)+4*(lane>>5)  [measured m74/m101].
// sel==2 (V) written TRANSPOSED to vT[b][h][t] (f16x4 stores along t).
__global__ __launch_bounds__(256, 2)
void qkv_gemm(const f16* __restrict__ xh, const f16* __restrict__ Wh,
              const float* __restrict__ bq, const float* __restrict__ bk,
              const float* __restrict__ bv, f16* __restrict__ qkv,
              f16* __restrict__ vT) {
  __shared__ __align__(16) f16 As[128 * 64];
  __shared__ __align__(16) f16 Bs[128 * 64];
  const int t = threadIdx.x;
  const int wave = t >> 6, lane = t & 63;
  const int l32 = lane & 31, half = lane >> 5;
  const int wm = (wave & 1) * 64, wn = (wave >> 1) * 64;
  const int sel = blockIdx.y >> 3;             // 0=q 1=k 2=v
  const int ntile = (blockIdx.y & 7) * 128;
  const int mtile = blockIdx.x * 128;

  const f16* Ab = xh + (long)mtile * H_;
  const f16* Bb = Wh + (long)sel * H_ * H_ + (long)ntile * H_;

  f32x16 acc[2][2] = {};

  for (int k0 = 0; k0 < H_; k0 += 64) {
    __syncthreads();
    stage_kmajor(Ab, H_, k0, t, As);
    stage_kmajor(Bb, H_, k0, t, Bs);
    __syncthreads();
#pragma unroll
    for (int kc2 = 0; kc2 < 4; kc2++) {  // K=16 step: kchunk pair (kc2*2, +half)
      const int kch = kc2 * 2 + half;
      f16x8 af[2], bf[2];
#pragma unroll
      for (int i = 0; i < 2; i++) {
        af[i] = *(const f16x8*)&As[(kch * 128 + wm + i * 32 + l32) * 8];
        bf[i] = *(const f16x8*)&Bs[(kch * 128 + wn + i * 32 + l32) * 8];
      }
#pragma unroll
      for (int i = 0; i < 2; i++)
#pragma unroll
        for (int j = 0; j < 2; j++)
          acc[i][j] = __builtin_amdgcn_mfma_f32_32x32x16_f16(af[i], bf[j], acc[i][j], 0, 0, 0);
    }
  }

  const float* bias = sel == 0 ? bq : (sel == 1 ? bk : bv);
  if (sel == 2) {
    // V transposed: vT[(b*H + n)*S + t_pos], b = m>>11, t_pos = m&2047.
#pragma unroll
    for (int jt = 0; jt < 2; jt++) {
      int n = ntile + wn + jt * 32 + l32;
      float bb = bias[n];
#pragma unroll
      for (int it = 0; it < 2; it++)
#pragma unroll
        for (int g = 0; g < 4; g++) {
          int m = mtile + wm + it * 32 + half * 4 + g * 8;
          f16x4 pack;
#pragma unroll
          for (int r = 0; r < 4; r++) pack[r] = (f16)(acc[it][jt][g * 4 + r] + bb);
          *(f16x4*)&vT[((long)(m >> 11) * H_ + n) * S_ + (m & 2047)] = pack;
        }
    }
  } else {
    f16* out = qkv + (long)sel * M_ * H_;
#pragma unroll
    for (int jt = 0; jt < 2; jt++) {
      int n = ntile + wn + jt * 32 + l32;
      float bb = bias[n];
#pragma unroll
      for (int it = 0; it < 2; it++)
#pragma unroll
        for (int g = 0; g < 4; g++) {
          int m = mtile + wm + it * 32 + half * 4 + g * 8;
#pragma unroll
          for (int r = 0; r < 4; r++)
            out[(long)(m + r) * H_ + n] = (f16)(acc[it][jt][g * 4 + r] + bb);
        }
    }
  }
}

// ---------------------------------------------------------------------------
// Generic batched NT fp16 GEMM (32x32x16 MFMA, K-major LDS):
// C[z][m][n] = alpha * sum_k A[z][m][k]*B[z][n][k]
// OUT_F16=1: store quantized fp16; OUT_F16=0: store fp32.
template <int OUT_F16>
__global__ __launch_bounds__(256, 2)
void gemm_nt(const f16* __restrict__ A, const f16* __restrict__ Bm,
             void* __restrict__ C, int lda, int ldb, int ldc, int K,
             long sA, long sB, long sC, float alpha) {
  __shared__ __align__(16) f16 As[128 * 64];
  __shared__ __align__(16) f16 Bs[128 * 64];
  const int t = threadIdx.x;
  const int wave = t >> 6, lane = t & 63;
  const int l32 = lane & 31, half = lane >> 5;
  const int wm = (wave & 1) * 64, wn = (wave >> 1) * 64;
  const f16* Ab = A + blockIdx.z * sA + (long)blockIdx.x * 128 * lda;
  const f16* Bb = Bm + blockIdx.z * sB + (long)blockIdx.y * 128 * ldb;
  f32x16 acc[2][2] = {};
  for (int k0 = 0; k0 < K; k0 += 64) {
    __syncthreads();
    stage_kmajor(Ab, lda, k0, t, As);
    stage_kmajor(Bb, ldb, k0, t, Bs);
    __syncthreads();
#pragma unroll
    for (int kc2 = 0; kc2 < 4; kc2++) {
      const int kch = kc2 * 2 + half;
      f16x8 af[2], bf[2];
#pragma unroll
      for (int i = 0; i < 2; i++) {
        af[i] = *(const f16x8*)&As[(kch * 128 + wm + i * 32 + l32) * 8];
        bf[i] = *(const f16x8*)&Bs[(kch * 128 + wn + i * 32 + l32) * 8];
      }
#pragma unroll
      for (int i = 0; i < 2; i++)
#pragma unroll
        for (int j = 0; j < 2; j++)
          acc[i][j] = __builtin_amdgcn_mfma_f32_32x32x16_f16(af[i], bf[j], acc[i][j], 0, 0, 0);
    }
  }
  const long mb = (long)blockIdx.x * 128 + wm;
  const long nb = (long)blockIdx.y * 128 + wn;
#pragma unroll
  for (int jt = 0; jt < 2; jt++) {
    long n = nb + jt * 32 + l32;
#pragma unroll
    for (int it = 0; it < 2; it++)
#pragma unroll
      for (int g = 0; g < 4; g++) {
        long m = mb + it * 32 + half * 4 + g * 8;
#pragma unroll
        for (int r = 0; r < 4; r++) {
          float v = acc[it][jt][g * 4 + r] * alpha;
          if (OUT_F16)
            ((f16*)C)[blockIdx.z * sC + (m + r) * ldc + n] = (f16)v;
          else
            ((float*)C)[blockIdx.z * sC + (m + r) * ldc + n] = v;
        }
      }
  }
}

// ---------------------------------------------------------------------------
// In-place row softmax over 2048 fp16 scores + quantize to fp16.
__global__ __launch_bounds__(256) void softmax_q(f16* __restrict__ sc) {
  const long row = blockIdx.x;
  f16* p = sc + row * S_;
  const int t = threadIdx.x;
  const int wave = t >> 6, lane = t & 63;
  f16x8 v = ((const f16x8*)p)[t];
  float f[8];
  float m = -3.0e38f;
#pragma unroll
  for (int c = 0; c < 8; c++) { f[c] = (float)v[c]; m = fmaxf(m, f[c]); }
#pragma unroll
  for (int o = 32; o > 0; o >>= 1) m = fmaxf(m, __shfl_xor(m, o));
  __shared__ float redm[4], reds[4];
  if (lane == 0) redm[wave] = m;
  __syncthreads();
  m = fmaxf(fmaxf(redm[0], redm[1]), fmaxf(redm[2], redm[3]));
  float s = 0.f, e[8];
#pragma unroll
  for (int c = 0; c < 8; c++) { e[c] = __expf(f[c] - m); s += e[c]; }
#pragma unroll
  for (int o = 32; o > 0; o >>= 1) s += __shfl_xor(s, o);
  if (lane == 0) reds[wave] = s;
  __syncthreads();
  s = reds[0] + reds[1] + reds[2] + reds[3];
  float inv = 1.0f / s;
  f16x8 ov;
#pragma unroll
  for (int c = 0; c < 8; c++) ov[c] = (f16)(e[c] * inv);
  ((f16x8*)p)[t] = ov;
}

// ---------------------------------------------------------------------------
extern "C" void kernel_launch(void* const* d_in, const int* in_sizes, int n_in,
                              void* d_out, int out_size, void* d_ws, size_t ws_size,
                              hipStream_t stream) {
  (void)in_sizes; (void)n_in; (void)out_size; (void)ws_size;
  const float* x  = (const float*)d_in[0];
  const float* Wq = (const float*)d_in[1];
  const float* bq = (const float*)d_in[2];
  const float* Wk = (const float*)d_in[3];
  const float* bk = (const float*)d_in[4];
  const float* Wv = (const float*)d_in[5];
  const float* bv = (const float*)d_in[6];

  char* ws = (char*)d_ws;
  f16* xh  = (f16*)ws; ws += (size_t)M_ * H_ * 2;          // 16 MiB
  f16* Wh  = (f16*)ws; ws += (size_t)3 * H_ * H_ * 2;      // 6 MiB
  f16* qkv = (f16*)ws; ws += (size_t)2 * M_ * H_ * 2;      // 32 MiB (q, k)
  f16* vT  = (f16*)ws; ws += (size_t)B_ * H_ * S_ * 2;     // 16 MiB
  f16* sc  = (f16*)ws; ws += (size_t)B_ * S_ * S_ * 2;     // 32 MiB (scores, then attn in-place)

  // 1) x, Wq/Wk/Wv -> fp16 in one launch
  downconvert_all<<<M_ * H_ / 1024 + 3 * H_ * H_ / 1024, 256, 0, stream>>>(
      x, Wq, Wk, Wv, xh, Wh);

  // 2) fused QKV projection + bias + quantize; V written transposed
  qkv_gemm<<<dim3(64, 24), 256, 0, stream>>>(xh, Wh, bq, bk, bv, qkv, vT);

  // 3) scores = quantize(q @ k^T / 32), per batch
  gemm_nt<1><<<dim3(16, 16, 4), 256, 0, stream>>>(
      qkv, qkv + (size_t)M_ * H_, sc, H_, H_, S_, H_,
      (long)S_ * H_, (long)S_ * H_, (long)S_ * S_, 0.03125f);

  // 4) attn = quantize(softmax(scores)) in-place
  softmax_q<<<M_, 256, 0, stream>>>(sc);

  // 5) out = attn @ vT^T  (fp32 epilogue straight to d_out)
  gemm_nt<0><<<dim3(16, 8, 4), 256, 0, stream>>>(
      sc, vT, d_out, S_, S_, H_, S_,
      (long)S_ * S_, (long)H_ * S_, (long)S_ * H_, 1.0f);
}

// Round 7
// 266.909 us; speedup vs baseline: 1.3187x; 1.3187x over previous
//
#include <hip/hip_runtime.h>
#include <hip/hip_fp16.h>

#define B_ 4
#define S_ 2048
#define H_ 1024
#define M_ (B_ * S_)  // 8192 flattened rows of x / q / k / v

typedef _Float16 f16;
typedef _Float16 f16x8 __attribute__((ext_vector_type(8)));
typedef _Float16 f16x4 __attribute__((ext_vector_type(4)));
typedef float f32x4 __attribute__((ext_vector_type(4)));
typedef float f32x16 __attribute__((ext_vector_type(16)));

typedef __attribute__((address_space(3))) unsigned int* lds_u32p;
typedef const __attribute__((address_space(1))) unsigned int* gbl_u32p;

// async global->LDS, 16B per lane; LDS dest is wave-uniform base + lane*16
__device__ __forceinline__ void stage16(const f16* g, f16* l) {
  __builtin_amdgcn_global_load_lds((gbl_u32p)g, (lds_u32p)l, 16, 0, 0);
}

// ---------------------------------------------------------------------------
// One launch: x (8192 blocks) then Wq/Wk/Wv (1024 blocks each) -> fp16 RNE.
__global__ __launch_bounds__(256) void downconvert_all(
    const float* __restrict__ x, const float* __restrict__ W0,
    const float* __restrict__ W1, const float* __restrict__ W2,
    f16* __restrict__ xh, f16* __restrict__ Wh) {
  const int b = blockIdx.x;
  const float* src;
  f16* dst;
  long i;
  if (b < M_ * H_ / 1024) {  // 8192 x-blocks
    src = x; dst = xh;
    i = (long)b * 256 + threadIdx.x;
  } else {
    const int wb = b - M_ * H_ / 1024;
    const int sel = wb >> 10;               // 1024 blocks per W
    src = sel == 0 ? W0 : (sel == 1 ? W1 : W2);
    dst = Wh + (long)sel * H_ * H_;
    i = (long)(wb & 1023) * 256 + threadIdx.x;
  }
  f32x4 v = ((const f32x4*)src)[i];
  f16x4 h;
#pragma unroll
  for (int c = 0; c < 4; c++) h[c] = (f16)v[c];
  ((f16x4*)dst)[i] = h;
}

// ---------------------------------------------------------------------------
// XOR-swizzled LDS tile, 128 rows x BK=64 (8 chunks of 16B per row):
//   LDS chunk  row*8 + (kc ^ (row&7))  holds global [row][kc*8 .. kc*8+8).
// Staging (global_load_lds forces LDS dest = base + lane*16): wave-instr lane
// l -> row W*8+(l>>3), chunk (l&7)^(l>>3): 8 full 128B row-segments per
// instruction (best coalescing). Fragment reads: every 8 consecutive lanes
// sweep all 8 bank-groups -> conflict-free b128.
__device__ __forceinline__ void stage_sw(const f16* base, long ld, int k0,
                                         int t, f16* lds) {
  const int l = t & 63, w = t >> 6;
#pragma unroll
  for (int c = 0; c < 4; c++) {
    const int W = c * 4 + w;                 // row-octet 0..15
    const int row = W * 8 + (l >> 3);
    const int kc = (l & 7) ^ (l >> 3);
    stage16(base + (long)row * ld + k0 + kc * 8, lds + (W * 64 + l) * 8);
  }
}

// ---------------------------------------------------------------------------
// Fused QKV projection, 32x32x16 MFMA, swizzled LDS.
// qkv[sel][m][n] = fp16round( x[m][:] . W_sel[n][:] + b_sel[n] ); pure fp16.
// NT GEMM, 128x128 tile, BK=64. Per wave: 64x64 = 2x2 of 32x32.
// Fragments: A[m=lane&31][k=(lane>>5)*8+j]; C/D col=lane&31,
// row=(reg&3)+8*(reg>>2)+4*(lane>>5)  [measured m74/m101; validated r4-r6].
// sel==2 (V) written TRANSPOSED to vT[b][h][t] (f16x4 stores along t).
__global__ __launch_bounds__(256, 2)
void qkv_gemm(const f16* __restrict__ xh, const f16* __restrict__ Wh,
              const float* __restrict__ bq, const float* __restrict__ bk,
              const float* __restrict__ bv, f16* __restrict__ qkv,
              f16* __restrict__ vT) {
  __shared__ __align__(16) f16 As[128 * 64];
  __shared__ __align__(16) f16 Bs[128 * 64];
  const int t = threadIdx.x;
  const int wave = t >> 6, lane = t & 63;
  const int l32 = lane & 31, half = lane >> 5;
  const int sw = l32 & 7;  // row&7 for this lane's fragment rows
  const int wm = (wave & 1) * 64, wn = (wave >> 1) * 64;
  const int sel = blockIdx.y >> 3;             // 0=q 1=k 2=v
  const int ntile = (blockIdx.y & 7) * 128;
  const int mtile = blockIdx.x * 128;

  const f16* Ab = xh + (long)mtile * H_;
  const f16* Bb = Wh + (long)sel * H_ * H_ + (long)ntile * H_;

  f32x16 acc[2][2] = {};

  for (int k0 = 0; k0 < H_; k0 += 64) {
    __syncthreads();
    stage_sw(Ab, H_, k0, t, As);
    stage_sw(Bb, H_, k0, t, Bs);
    __syncthreads();
#pragma unroll
    for (int kc2 = 0; kc2 < 4; kc2++) {  // K=16 step; lane reads chunk kc2*2+half
      const int kch = (kc2 * 2 + half) ^ sw;
      f16x8 af[2], bf[2];
#pragma unroll
      for (int i = 0; i < 2; i++) {
        af[i] = *(const f16x8*)&As[((wm + i * 32 + l32) * 8 + kch) * 8];
        bf[i] = *(const f16x8*)&Bs[((wn + i * 32 + l32) * 8 + kch) * 8];
      }
#pragma unroll
      for (int i = 0; i < 2; i++)
#pragma unroll
        for (int j = 0; j < 2; j++)
          acc[i][j] = __builtin_amdgcn_mfma_f32_32x32x16_f16(af[i], bf[j], acc[i][j], 0, 0, 0);
    }
  }

  const float* bias = sel == 0 ? bq : (sel == 1 ? bk : bv);
  if (sel == 2) {
    // V transposed: vT[(b*H + n)*S + t_pos], b = m>>11, t_pos = m&2047.
#pragma unroll
    for (int jt = 0; jt < 2; jt++) {
      int n = ntile + wn + jt * 32 + l32;
      float bb = bias[n];
#pragma unroll
      for (int it = 0; it < 2; it++)
#pragma unroll
        for (int g = 0; g < 4; g++) {
          int m = mtile + wm + it * 32 + half * 4 + g * 8;
          f16x4 pack;
#pragma unroll
          for (int r = 0; r < 4; r++) pack[r] = (f16)(acc[it][jt][g * 4 + r] + bb);
          *(f16x4*)&vT[((long)(m >> 11) * H_ + n) * S_ + (m & 2047)] = pack;
        }
    }
  } else {
    f16* out = qkv + (long)sel * M_ * H_;
#pragma unroll
    for (int jt = 0; jt < 2; jt++) {
      int n = ntile + wn + jt * 32 + l32;
      float bb = bias[n];
#pragma unroll
      for (int it = 0; it < 2; it++)
#pragma unroll
        for (int g = 0; g < 4; g++) {
          int m = mtile + wm + it * 32 + half * 4 + g * 8;
#pragma unroll
          for (int r = 0; r < 4; r++)
            out[(long)(m + r) * H_ + n] = (f16)(acc[it][jt][g * 4 + r] + bb);
        }
    }
  }
}

// ---------------------------------------------------------------------------
// Generic batched NT fp16 GEMM (32x32x16 MFMA, swizzled LDS):
// C[z][m][n] = alpha * sum_k A[z][m][k]*B[z][n][k]
// OUT_F16=1: store quantized fp16; OUT_F16=0: store fp32.
template <int OUT_F16>
__global__ __launch_bounds__(256, 2)
void gemm_nt(const f16* __restrict__ A, const f16* __restrict__ Bm,
             void* __restrict__ C, int lda, int ldb, int ldc, int K,
             long sA, long sB, long sC, float alpha) {
  __shared__ __align__(16) f16 As[128 * 64];
  __shared__ __align__(16) f16 Bs[128 * 64];
  const int t = threadIdx.x;
  const int wave = t >> 6, lane = t & 63;
  const int l32 = lane & 31, half = lane >> 5;
  const int sw = l32 & 7;
  const int wm = (wave & 1) * 64, wn = (wave >> 1) * 64;
  const f16* Ab = A + blockIdx.z * sA + (long)blockIdx.x * 128 * lda;
  const f16* Bb = Bm + blockIdx.z * sB + (long)blockIdx.y * 128 * ldb;
  f32x16 acc[2][2] = {};
  for (int k0 = 0; k0 < K; k0 += 64) {
    __syncthreads();
    stage_sw(Ab, lda, k0, t, As);
    stage_sw(Bb, ldb, k0, t, Bs);
    __syncthreads();
#pragma unroll
    for (int kc2 = 0; kc2 < 4; kc2++) {
      const int kch = (kc2 * 2 + half) ^ sw;
      f16x8 af[2], bf[2];
#pragma unroll
      for (int i = 0; i < 2; i++) {
        af[i] = *(const f16x8*)&As[((wm + i * 32 + l32) * 8 + kch) * 8];
        bf[i] = *(const f16x8*)&Bs[((wn + i * 32 + l32) * 8 + kch) * 8];
      }
#pragma unroll
      for (int i = 0; i < 2; i++)
#pragma unroll
        for (int j = 0; j < 2; j++)
          acc[i][j] = __builtin_amdgcn_mfma_f32_32x32x16_f16(af[i], bf[j], acc[i][j], 0, 0, 0);
    }
  }
  const long mb = (long)blockIdx.x * 128 + wm;
  const long nb = (long)blockIdx.y * 128 + wn;
#pragma unroll
  for (int jt = 0; jt < 2; jt++) {
    long n = nb + jt * 32 + l32;
#pragma unroll
    for (int it = 0; it < 2; it++)
#pragma unroll
      for (int g = 0; g < 4; g++) {
        long m = mb + it * 32 + half * 4 + g * 8;
#pragma unroll
        for (int r = 0; r < 4; r++) {
          float v = acc[it][jt][g * 4 + r] * alpha;
          if (OUT_F16)
            ((f16*)C)[blockIdx.z * sC + (m + r) * ldc + n] = (f16)v;
          else
            ((float*)C)[blockIdx.z * sC + (m + r) * ldc + n] = v;
        }
      }
  }
}

// ---------------------------------------------------------------------------
// In-place row softmax over 2048 fp16 scores + quantize to fp16.
__global__ __launch_bounds__(256) void softmax_q(f16* __restrict__ sc) {
  const long row = blockIdx.x;
  f16* p = sc + row * S_;
  const int t = threadIdx.x;
  const int wave = t >> 6, lane = t & 63;
  f16x8 v = ((const f16x8*)p)[t];
  float f[8];
  float m = -3.0e38f;
#pragma unroll
  for (int c = 0; c < 8; c++) { f[c] = (float)v[c]; m = fmaxf(m, f[c]); }
#pragma unroll
  for (int o = 32; o > 0; o >>= 1) m = fmaxf(m, __shfl_xor(m, o));
  __shared__ float redm[4], reds[4];
  if (lane == 0) redm[wave] = m;
  __syncthreads();
  m = fmaxf(fmaxf(redm[0], redm[1]), fmaxf(redm[2], redm[3]));
  float s = 0.f, e[8];
#pragma unroll
  for (int c = 0; c < 8; c++) { e[c] = __expf(f[c] - m); s += e[c]; }
#pragma unroll
  for (int o = 32; o > 0; o >>= 1) s += __shfl_xor(s, o);
  if (lane == 0) reds[wave] = s;
  __syncthreads();
  s = reds[0] + reds[1] + reds[2] + reds[3];
  float inv = 1.0f / s;
  f16x8 ov;
#pragma unroll
  for (int c = 0; c < 8; c++) ov[c] = (f16)(e[c] * inv);
  ((f16x8*)p)[t] = ov;
}

// ---------------------------------------------------------------------------
extern "C" void kernel_launch(void* const* d_in, const int* in_sizes, int n_in,
                              void* d_out, int out_size, void* d_ws, size_t ws_size,
                              hipStream_t stream) {
  (void)in_sizes; (void)n_in; (void)out_size; (void)ws_size;
  const float* x  = (const float*)d_in[0];
  const float* Wq = (const float*)d_in[1];
  const float* bq = (const float*)d_in[2];
  const float* Wk = (const float*)d_in[3];
  const float* bk = (const float*)d_in[4];
  const float* Wv = (const float*)d_in[5];
  const float* bv = (const float*)d_in[6];

  char* ws = (char*)d_ws;
  f16* xh  = (f16*)ws; ws += (size_t)M_ * H_ * 2;          // 16 MiB
  f16* Wh  = (f16*)ws; ws += (size_t)3 * H_ * H_ * 2;      // 6 MiB
  f16* qkv = (f16*)ws; ws += (size_t)2 * M_ * H_ * 2;      // 32 MiB (q, k)
  f16* vT  = (f16*)ws; ws += (size_t)B_ * H_ * S_ * 2;     // 16 MiB
  f16* sc  = (f16*)ws; ws += (size_t)B_ * S_ * S_ * 2;     // 32 MiB (scores, then attn in-place)

  // 1) x, Wq/Wk/Wv -> fp16 in one launch
  downconvert_all<<<M_ * H_ / 1024 + 3 * H_ * H_ / 1024, 256, 0, stream>>>(
      x, Wq, Wk, Wv, xh, Wh);

  // 2) fused QKV projection + bias + quantize; V written transposed
  qkv_gemm<<<dim3(64, 24), 256, 0, stream>>>(xh, Wh, bq, bk, bv, qkv, vT);

  // 3) scores = quantize(q @ k^T / 32), per batch
  gemm_nt<1><<<dim3(16, 16, 4), 256, 0, stream>>>(
      qkv, qkv + (size_t)M_ * H_, sc, H_, H_, S_, H_,
      (long)S_ * H_, (long)S_ * H_, (long)S_ * S_, 0.03125f);

  // 4) attn = quantize(softmax(scores)) in-place
  softmax_q<<<M_, 256, 0, stream>>>(sc);

  // 5) out = attn @ vT^T  (fp32 epilogue straight to d_out)
  gemm_nt<0><<<dim3(16, 8, 4), 256, 0, stream>>>(
      sc, vT, d_out, S_, S_, H_, S_,
      (long)S_ * S_, (long)H_ * S_, (long)S_ * H_, 1.0f);
}